// Round 6
// baseline (190.683 us; speedup 1.0000x reference)
//
#include <hip/hip_runtime.h>
#include <hip/hip_bf16.h>
#include <stdint.h>

#define NHEADS 8
#define INDIM 512
#define EMB 512
#define BSZ 4
#define NQS 2048
#define GS 2048

// 0.125 * log2(e): folded into W_query so attention exp is a bare 2^x
#define ALPHA_F 0.18033688011112042f

#if __has_builtin(__builtin_amdgcn_exp2f)
#define EXP2(x) __builtin_amdgcn_exp2f(x)
#else
#define EXP2(x) __expf((x)*0.69314718056f)
#endif

typedef short bf16x8 __attribute__((ext_vector_type(8)));
typedef float f32x4 __attribute__((ext_vector_type(4)));

static __device__ __forceinline__ unsigned short f2bf(float f) {
  unsigned int u = __builtin_bit_cast(unsigned int, f);
  unsigned int rounding = 0x7FFFu + ((u >> 16) & 1u);
  u += rounding;
  return (unsigned short)(u >> 16);
}

typedef __attribute__((address_space(3))) void lds_void;
typedef __attribute__((address_space(1))) const void gm_void;
static __device__ __forceinline__ void gll16(const void* g, void* s) {
  __builtin_amdgcn_global_load_lds((gm_void*)g, (lds_void*)s, 16, 0, 0);
}

// ---------------- prep kernels ----------------

// both f32->bf16 converts in one launch: blocks [0,2048) -> a, [2048,4096) -> b
__global__ void k_cvt2(const float4* __restrict__ a, const float4* __restrict__ b,
                       ushort4* __restrict__ da, ushort4* __restrict__ db) {
  int half = blockIdx.x >> 11;
  int i = (blockIdx.x & 2047) * blockDim.x + threadIdx.x;
  const float4* src = half ? b : a;
  ushort4* dst = half ? db : da;
  for (; i < 8192 * 512 / 4; i += 2048 * 256) {
    float4 v = src[i];
    ushort4 o;
    o.x = f2bf(v.x); o.y = f2bf(v.y); o.z = f2bf(v.z); o.w = f2bf(v.w);
    dst[i] = o;
  }
}

// all weight packs in one kernel. wqt scaled by ALPHA. wkvt = [wk(512) | wv(512)] rows.
__global__ void k_pack_all(const float* __restrict__ wq, const float* __restrict__ wk,
                           const float* __restrict__ wv, const float* __restrict__ wo,
                           unsigned short* __restrict__ wqt, unsigned short* __restrict__ wkvt,
                           unsigned short* __restrict__ wot) {
  int id = blockIdx.x * blockDim.x + threadIdx.x;
  int which = id >> 18, r = id & 262143;
  int k = r & 511, n = r >> 9;
  int h = n >> 6, j = n & 63;
  if (which == 0) wqt[r] = f2bf(wq[h * 32768 + k * 64 + j] * ALPHA_F);
  else if (which == 1) wkvt[r] = f2bf(wk[h * 32768 + k * 64 + j]);
  else if (which == 2) wkvt[262144 + r] = f2bf(wv[h * 32768 + k * 64 + j]);
  else wot[r] = f2bf(wo[k * 512 + n]);
}

// detect mask dtype: 1 => 1-byte bools, 0 => int32
__global__ void k_detect(const unsigned int* __restrict__ m, unsigned int* __restrict__ flag) {
  __shared__ unsigned int s;
  if (threadIdx.x == 0) s = 0u;
  __syncthreads();
  unsigned int any = 0u;
  for (int i = threadIdx.x; i < 2048; i += blockDim.x) any |= (m[i] > 1u) ? 1u : 0u;
  if (any) atomicOr(&s, 1u);
  __syncthreads();
  if (threadIdx.x == 0) *flag = s;
}

// bit-pack mask: maskB[(b*NQS+q)*32 + g64] bit (g&63) = mask(b,q,g)
__global__ void k_maskpack(const unsigned char* __restrict__ m8, const int* __restrict__ m32,
                           const unsigned int* __restrict__ flag,
                           unsigned long long* __restrict__ mb) {
  size_t i = (size_t)blockIdx.x * blockDim.x + threadIdx.x;
  bool bytes = (*flag != 0u);
  int v = bytes ? (int)m8[i] : m32[i];
  unsigned long long bal = __ballot(v != 0);
  if ((threadIdx.x & 63) == 0) mb[i >> 6] = bal;
}

// ---------------- GEMM3: C[m][n] = sum_k A[m][k]*Bt[n][k]; K=512, bf16 ----------------
// BM=64, BN=128, BK=64, 256 thr (4 waves: wr=w>>1, wc=w&1), gll16 staging,
// fragment-linear LDS (chunk = rb*128 + kcc*16 + c, 16B chunks), 2-phase prefetch, 8 iters.
// MODE 0: bf16 C. MODE 1: f32 C. MODE 4: N=1024 fused KV (cols>=512 -> transposed C2).

template <int MODE>
__global__ __launch_bounds__(256) void k_gemm3(const unsigned short* __restrict__ A,
                                               const unsigned short* __restrict__ Bt,
                                               void* __restrict__ C, void* __restrict__ C2) {
  __shared__ unsigned short As[2][4096];   // 64 x 64
  __shared__ unsigned short Bs[2][8192];   // 128 x 64
  int m0 = blockIdx.x * 64, n0 = blockIdx.y * 128;
  int t = threadIdx.x;
  int w = t >> 6, l = t & 63, c = l & 15, lg = l >> 4;
  int wr = w >> 1, wc = w & 1;

  // staging: chunk id = rb*128 + kcc*16 + cc  <->  row rb*16+cc, k-chunk kcc (8 shorts)
  int rbA = t >> 7, kcc = (t >> 4) & 7, cc = t & 15;
  const unsigned short* aG = A + (size_t)(m0 + rbA * 16 + cc) * 512 + kcc * 8;
  const unsigned short* bG = Bt + (size_t)(n0 + rbA * 16 + cc) * 512 + kcc * 8;
  int ldsOff = w * 1024 + (t & 63) * 16;   // byte offset of this thread's first chunk

  f32x4 acc[2][4];
#pragma unroll
  for (int mi = 0; mi < 2; mi++)
#pragma unroll
    for (int ni = 0; ni < 4; ni++) acc[mi][ni] = {0.f, 0.f, 0.f, 0.f};

  // prologue stage k0=0
  gll16(aG, (char*)As[0] + ldsOff);
  gll16(aG + 32 * 512, (char*)As[0] + ldsOff + 4096);
  gll16(bG, (char*)Bs[0] + ldsOff);
  gll16(bG + 32 * 512, (char*)Bs[0] + ldsOff + 4096);
  gll16(bG + 64 * 512, (char*)Bs[0] + ldsOff + 8192);
  gll16(bG + 96 * 512, (char*)Bs[0] + ldsOff + 12288);
  __syncthreads();

  for (int kk = 0; kk < 8; kk++) {
    int cur = kk & 1;
    if (kk < 7) {
      int ko = (kk + 1) * 64;
      gll16(aG + ko, (char*)As[cur ^ 1] + ldsOff);
      gll16(aG + ko + 32 * 512, (char*)As[cur ^ 1] + ldsOff + 4096);
      gll16(bG + ko, (char*)Bs[cur ^ 1] + ldsOff);
      gll16(bG + ko + 32 * 512, (char*)Bs[cur ^ 1] + ldsOff + 4096);
      gll16(bG + ko + 64 * 512, (char*)Bs[cur ^ 1] + ldsOff + 8192);
      gll16(bG + ko + 96 * 512, (char*)Bs[cur ^ 1] + ldsOff + 12288);
    }
    bf16x8 af[2][2], bfr[4][2];
#pragma unroll
    for (int kc = 0; kc < 2; kc++) {
#pragma unroll
      for (int mi = 0; mi < 2; mi++)
        af[mi][kc] = *(const bf16x8*)((const char*)As[cur] + ((wr * 2 + mi) * 128 + (kc * 4 + lg) * 16 + c) * 16);
#pragma unroll
      for (int ni = 0; ni < 4; ni++)
        bfr[ni][kc] = *(const bf16x8*)((const char*)Bs[cur] + ((wc * 4 + ni) * 128 + (kc * 4 + lg) * 16 + c) * 16);
    }
#pragma unroll
    for (int kc = 0; kc < 2; kc++)
#pragma unroll
      for (int mi = 0; mi < 2; mi++)
#pragma unroll
        for (int ni = 0; ni < 4; ni++)
          acc[mi][ni] = __builtin_amdgcn_mfma_f32_16x16x32_bf16(af[mi][kc], bfr[ni][kc], acc[mi][ni], 0, 0, 0);
    __syncthreads();
  }

#pragma unroll
  for (int mi = 0; mi < 2; mi++)
#pragma unroll
    for (int ni = 0; ni < 4; ni++) {
      int row = m0 + wr * 32 + mi * 16 + 4 * lg;
      int col = n0 + wc * 64 + ni * 16 + c;
      if constexpr (MODE == 1) {
#pragma unroll
        for (int r = 0; r < 4; r++)
          ((float*)C)[(size_t)(row + r) * 512 + col] = acc[mi][ni][r];
      } else if constexpr (MODE == 0) {
#pragma unroll
        for (int r = 0; r < 4; r++)
          ((unsigned short*)C)[(size_t)(row + r) * 512 + col] = f2bf(acc[mi][ni][r]);
      } else {  // MODE 4
        if (n0 < 512) {
#pragma unroll
          for (int r = 0; r < 4; r++)
            ((unsigned short*)C)[(size_t)(row + r) * 512 + col] = f2bf(acc[mi][ni][r]);
        } else {
          int col5 = col - 512, hd2 = col5 >> 6, vv = col5 & 63;
          int bb = row >> 11, g = row & 2047;
          ushort4 u;
          u.x = f2bf(acc[mi][ni][0]);
          u.y = f2bf(acc[mi][ni][1]);
          u.z = f2bf(acc[mi][ni][2]);
          u.w = f2bf(acc[mi][ni][3]);
          *(ushort4*)((unsigned short*)C2 + (size_t)((bb * 8 + hd2) * 64 + vv) * GS + g) = u;
        }
      }
    }
}

// ---------------- flash attention (swapped-operand, 16 q-rows/wave, 4 blocks/CU) ----------------
// grid 1024: fid = (bid&7)*128 + bid>>3 (XCD-bijective). qtile = fid&31 (64 q), bh = fid>>5.
// Qp pre-scaled by 0.125*log2(e) -> P = 2^(S^T).
__global__ __launch_bounds__(256, 4) void k_attn3(const unsigned short* __restrict__ Qp,
                                                  const unsigned short* __restrict__ Kp,
                                                  const unsigned short* __restrict__ Vt,
                                                  const unsigned long long* __restrict__ maskB,
                                                  unsigned short* __restrict__ Hd) {
  __shared__ unsigned short Ksh[2][4096];   // 8KB per buffer
  __shared__ unsigned short Vsh[2][4096];
  __shared__ unsigned short Plds[4][1024];  // 2KB per wave (16q x 64g)

  int bid = blockIdx.x;
  int fid = (bid & 7) * 128 + (bid >> 3);
  int qtile = fid & 31;
  int bh = fid >> 5;
  int b = bh >> 3, hd = bh & 7;

  int t = threadIdx.x;
  int w = t >> 6, l = t & 63, c = l & 15, lg = l >> 4;
  int qw = qtile * 64 + w * 16;

  bf16x8 qb[2];
#pragma unroll
  for (int kc = 0; kc < 2; kc++)
    qb[kc] = *(const bf16x8*)(Qp + (size_t)(b * NQS + qw + c) * 512 + hd * 64 + kc * 32 + lg * 8);

  int sr = ((t >> 7) & 1) * 16 + (t & 15);
  int sdc = ((t >> 6) & 1) * 4 + ((t >> 4) & 3);
  const unsigned short* kgbase = Kp + (size_t)(b * GS + sr) * 512 + hd * 64 + sdc * 8;
  const unsigned short* vgbase = Vt + (size_t)(bh * 64 + sr) * GS + sdc * 8;
  char* kdst[2] = {(char*)&Ksh[0][0] + w * 1024, (char*)&Ksh[1][0] + w * 1024};
  char* vdst[2] = {(char*)&Vsh[0][0] + w * 1024, (char*)&Vsh[1][0] + w * 1024};

  f32x4 o[4];
#pragma unroll
  for (int vt = 0; vt < 4; vt++) o[vt] = {0.f, 0.f, 0.f, 0.f};
  float lrow = 0.f;

  gll16(kgbase, kdst[0]);
  gll16(kgbase + 32 * 512, kdst[0] + 4096);
  gll16(vgbase, vdst[0]);
  gll16(vgbase + 32 * GS, vdst[0] + 4096);
  __syncthreads();

  for (int kt = 0; kt < 32; kt++) {
    int cur = kt & 1;
    if (kt < 31) {
      size_t g0 = (size_t)(kt + 1) * 64;
      const unsigned short* kg = kgbase + g0 * 512;
      const unsigned short* vg = vgbase + g0;
      char* kd = kdst[cur ^ 1];
      char* vd = vdst[cur ^ 1];
      gll16(kg, kd);
      gll16(kg + 32 * 512, kd + 4096);
      gll16(vg, vd);
      gll16(vg + 32 * GS, vd + 4096);
    }
    unsigned long long wm = maskB[(size_t)(b * NQS + qw + c) * 32 + kt];

    // S^T = K * Q^T : s[gt], C layout col=q=l&15, row=g=4*lg+reg
    const unsigned short* Kc = &Ksh[cur][0];
    f32x4 s[4];
#pragma unroll
    for (int gt = 0; gt < 4; gt++) s[gt] = {0.f, 0.f, 0.f, 0.f};
    __builtin_amdgcn_s_setprio(1);
#pragma unroll
    for (int kc = 0; kc < 2; kc++) {
      bf16x8 ka[4];
#pragma unroll
      for (int gt = 0; gt < 4; gt++)
        ka[gt] = *(const bf16x8*)(Kc + ((gt * 2 + kc) * 64 + l) * 8);
#pragma unroll
      for (int gt = 0; gt < 4; gt++)
        s[gt] = __builtin_amdgcn_mfma_f32_16x16x32_bf16(ka[gt], qb[kc], s[gt], 0, 0, 0);
    }
    __builtin_amdgcn_s_setprio(0);

    // masked 2^s (no running max: scores bounded; all-masked rows -> l=0 -> out=0)
    float ls = 0.f;
#pragma unroll
    for (int gt = 0; gt < 4; gt++) {
      unsigned nib = (unsigned)(wm >> (gt * 16));
      f32x4 pv;
#pragma unroll
      for (int r = 0; r < 4; r++) {
        float e = EXP2(s[gt][r]);
        unsigned bitm = (nib >> (4 * lg + r)) & 1u;
        pv[r] = bitm ? 0.f : e;
        ls += pv[r];
      }
      s[gt] = pv;
    }
    lrow += ls;

    // pack P^T (bf16, v_cvt_pk) into per-wave fragment-linear LDS
#pragma unroll
    for (int gt = 0; gt < 4; gt++) {
      uint2 wp;
      asm("v_cvt_pk_bf16_f32 %0, %1, %2" : "=v"(wp.x) : "v"(s[gt][0]), "v"(s[gt][1]));
      asm("v_cvt_pk_bf16_f32 %0, %1, %2" : "=v"(wp.y) : "v"(s[gt][2]), "v"(s[gt][3]));
      int chunk = (gt >> 1) * 64 + ((gt & 1) * 2 + (lg >> 1)) * 16 + c;
      *(uint2*)((char*)&Plds[w][0] + chunk * 16 + 8 * (lg & 1)) = wp;
    }
    asm volatile("s_waitcnt lgkmcnt(0)" ::: "memory");
    __builtin_amdgcn_sched_barrier(0);

    // O^T += V^T * P^T
    const unsigned short* Vc = &Vsh[cur][0];
    __builtin_amdgcn_s_setprio(1);
#pragma unroll
    for (int kc2 = 0; kc2 < 2; kc2++) {
      bf16x8 pb = *(const bf16x8*)((const char*)&Plds[w][0] + (kc2 * 64 + l) * 16);
      bf16x8 va[4];
#pragma unroll
      for (int vt = 0; vt < 4; vt++)
        va[vt] = *(const bf16x8*)(Vc + ((vt * 2 + kc2) * 64 + l) * 8);
#pragma unroll
      for (int vt = 0; vt < 4; vt++)
        o[vt] = __builtin_amdgcn_mfma_f32_16x16x32_bf16(va[vt], pb, o[vt], 0, 0, 0);
    }
    __builtin_amdgcn_s_setprio(0);
    __syncthreads();
  }

  // epilogue: reduce l across the 4 lanes sharing q, normalize, store
  {
    float lr = lrow;
    lr += __shfl_xor(lr, 16);
    lr += __shfl_xor(lr, 32);
    float inv = lr > 0.f ? 1.0f / lr : 0.f;
#pragma unroll
    for (int vt = 0; vt < 4; vt++) {
      ushort4 u;
      u.x = f2bf(o[vt][0] * inv);
      u.y = f2bf(o[vt][1] * inv);
      u.z = f2bf(o[vt][2] * inv);
      u.w = f2bf(o[vt][3] * inv);
      *(ushort4*)(Hd + (size_t)(b * NQS + qw + c) * 512 + hd * 64 + vt * 16 + 4 * lg) = u;
    }
  }
}

// ---------------- launch ----------------

extern "C" void kernel_launch(void* const* d_in, const int* in_sizes, int n_in,
                              void* d_out, int out_size, void* d_ws, size_t ws_size,
                              hipStream_t stream) {
  const float* q = (const float*)d_in[0];
  const float* h = (const float*)d_in[1];
  const void* mask = d_in[2];
  const float* wq = (const float*)d_in[3];
  const float* wk = (const float*)d_in[4];
  const float* wv = (const float*)d_in[5];
  const float* wo = (const float*)d_in[6];
  float* out = (float*)d_out;

  unsigned short* qb_ = (unsigned short*)d_ws;       // 8192*512 each
  unsigned short* hb_ = qb_ + 8192 * 512;
  unsigned short* Qp = hb_ + 8192 * 512;
  unsigned short* Kp = Qp + 8192 * 512;
  unsigned short* Vtp = Kp + 8192 * 512;             // transposed V: [(b*8+h)*64+v][2048]
  unsigned short* Hd = Vtp + 8192 * 512;
  unsigned short* wqt = Hd + 8192 * 512;
  unsigned short* wkvt = wqt + 512 * 512;            // [1024][512]: wk rows 0-511, wv rows 512-1023
  unsigned short* wot = wkvt + 1024 * 512;
  unsigned long long* maskB = (unsigned long long*)(wot + 512 * 512);  // 4*2048*32 u64 = 2 MB
  unsigned int* flag = (unsigned int*)(maskB + (size_t)4 * 2048 * 32);

  k_detect<<<1, 256, 0, stream>>>((const unsigned int*)mask, flag);
  k_cvt2<<<4096, 256, 0, stream>>>((const float4*)q, (const float4*)h, (ushort4*)qb_, (ushort4*)hb_);
  k_pack_all<<<4096, 256, 0, stream>>>(wq, wk, wv, wo, wqt, wkvt, wot);
  k_maskpack<<<65536, 256, 0, stream>>>((const unsigned char*)mask, (const int*)mask, flag, maskB);
  dim3 gq(128, 4);
  k_gemm3<0><<<gq, 256, 0, stream>>>(qb_, wqt, Qp, nullptr);
  dim3 gkv(128, 8);
  k_gemm3<4><<<gkv, 256, 0, stream>>>(hb_, wkvt, Kp, Vtp);
  k_attn3<<<1024, 256, 0, stream>>>(Qp, Kp, Vtp, maskB, Hd);
  dim3 go(128, 4);
  k_gemm3<1><<<go, 256, 0, stream>>>(Hd, wot, out, nullptr);
}

// Round 7
// 181.525 us; speedup vs baseline: 1.0504x; 1.0504x over previous
//
#include <hip/hip_runtime.h>
#include <hip/hip_bf16.h>
#include <stdint.h>

#define NHEADS 8
#define INDIM 512
#define EMB 512
#define BSZ 4
#define NQS 2048
#define GS 2048

// 0.125 * log2(e): folded into W_query so attention exp is a bare 2^x
#define ALPHA_F 0.18033688011112042f

#if __has_builtin(__builtin_amdgcn_exp2f)
#define EXP2(x) __builtin_amdgcn_exp2f(x)
#else
#define EXP2(x) __expf((x)*0.69314718056f)
#endif

typedef short bf16x8 __attribute__((ext_vector_type(8)));
typedef float f32x4 __attribute__((ext_vector_type(4)));

static __device__ __forceinline__ unsigned short f2bf(float f) {
  unsigned int u = __builtin_bit_cast(unsigned int, f);
  unsigned int rounding = 0x7FFFu + ((u >> 16) & 1u);
  u += rounding;
  return (unsigned short)(u >> 16);
}

typedef __attribute__((address_space(3))) void lds_void;
typedef __attribute__((address_space(1))) const void gm_void;
static __device__ __forceinline__ void gll16(const void* g, void* s) {
  __builtin_amdgcn_global_load_lds((gm_void*)g, (lds_void*)s, 16, 0, 0);
}

// ---------------- prep kernels ----------------

// both f32->bf16 converts in one launch: blocks [0,2048) -> a, [2048,4096) -> b
__global__ void k_cvt2(const float4* __restrict__ a, const float4* __restrict__ b,
                       ushort4* __restrict__ da, ushort4* __restrict__ db) {
  int half = blockIdx.x >> 11;
  int i = (blockIdx.x & 2047) * blockDim.x + threadIdx.x;
  const float4* src = half ? b : a;
  ushort4* dst = half ? db : da;
  for (; i < 8192 * 512 / 4; i += 2048 * 256) {
    float4 v = src[i];
    ushort4 o;
    o.x = f2bf(v.x); o.y = f2bf(v.y); o.z = f2bf(v.z); o.w = f2bf(v.w);
    dst[i] = o;
  }
}

// all weight packs in one kernel. wqt scaled by ALPHA. wkvt = [wk(512) | wv(512)] rows.
__global__ void k_pack_all(const float* __restrict__ wq, const float* __restrict__ wk,
                           const float* __restrict__ wv, const float* __restrict__ wo,
                           unsigned short* __restrict__ wqt, unsigned short* __restrict__ wkvt,
                           unsigned short* __restrict__ wot) {
  int id = blockIdx.x * blockDim.x + threadIdx.x;
  int which = id >> 18, r = id & 262143;
  int k = r & 511, n = r >> 9;
  int h = n >> 6, j = n & 63;
  if (which == 0) wqt[r] = f2bf(wq[h * 32768 + k * 64 + j] * ALPHA_F);
  else if (which == 1) wkvt[r] = f2bf(wk[h * 32768 + k * 64 + j]);
  else if (which == 2) wkvt[262144 + r] = f2bf(wv[h * 32768 + k * 64 + j]);
  else wot[r] = f2bf(wo[k * 512 + n]);
}

// detect mask dtype: 1 => 1-byte bools, 0 => int32
__global__ void k_detect(const unsigned int* __restrict__ m, unsigned int* __restrict__ flag) {
  __shared__ unsigned int s;
  if (threadIdx.x == 0) s = 0u;
  __syncthreads();
  unsigned int any = 0u;
  for (int i = threadIdx.x; i < 2048; i += blockDim.x) any |= (m[i] > 1u) ? 1u : 0u;
  if (any) atomicOr(&s, 1u);
  __syncthreads();
  if (threadIdx.x == 0) *flag = s;
}

// bit-pack mask: maskB[(b*NQS+q)*32 + g64] bit (g&63) = mask(b,q,g)
__global__ void k_maskpack(const unsigned char* __restrict__ m8, const int* __restrict__ m32,
                           const unsigned int* __restrict__ flag,
                           unsigned long long* __restrict__ mb) {
  size_t i = (size_t)blockIdx.x * blockDim.x + threadIdx.x;
  bool bytes = (*flag != 0u);
  int v = bytes ? (int)m8[i] : m32[i];
  unsigned long long bal = __ballot(v != 0);
  if ((threadIdx.x & 63) == 0) mb[i >> 6] = bal;
}

// ---------------- GEMM3: C[m][n] = sum_k A[m][k]*Bt[n][k]; K=512, bf16 ----------------
// BM=64, BN=128, BK=64, 256 thr, gll16 staging, fragment-linear LDS, counted-prefetch:
// per iter: vmcnt(0) [waits loads issued one compute-phase ago] -> raw s_barrier ->
// issue next tile -> ds_read frags -> MFMA. One barrier per iter, no drain of fresh loads.
// MODE 0: bf16 C. MODE 1: f32 C. MODE 4: N=1024 fused KV (cols>=512 -> transposed C2).

template <int MODE>
__global__ __launch_bounds__(256) void k_gemm3(const unsigned short* __restrict__ A,
                                               const unsigned short* __restrict__ Bt,
                                               void* __restrict__ C, void* __restrict__ C2) {
  __shared__ unsigned short As[2][4096];   // 64 x 64
  __shared__ unsigned short Bs[2][8192];   // 128 x 64
  int m0 = blockIdx.x * 64, n0 = blockIdx.y * 128;
  int t = threadIdx.x;
  int w = t >> 6, l = t & 63, c = l & 15, lg = l >> 4;
  int wr = w >> 1, wc = w & 1;

  // staging: chunk id = rb*128 + kcc*16 + cc  <->  row rb*16+cc, k-chunk kcc (8 shorts)
  int rbA = t >> 7, kcc = (t >> 4) & 7, cc = t & 15;
  const unsigned short* aG = A + (size_t)(m0 + rbA * 16 + cc) * 512 + kcc * 8;
  const unsigned short* bG = Bt + (size_t)(n0 + rbA * 16 + cc) * 512 + kcc * 8;
  int ldsOff = w * 1024 + (t & 63) * 16;   // byte offset of this thread's first chunk

  f32x4 acc[2][4];
#pragma unroll
  for (int mi = 0; mi < 2; mi++)
#pragma unroll
    for (int ni = 0; ni < 4; ni++) acc[mi][ni] = {0.f, 0.f, 0.f, 0.f};

  // prologue stage k0=0 into buf0
  gll16(aG, (char*)As[0] + ldsOff);
  gll16(aG + 32 * 512, (char*)As[0] + ldsOff + 4096);
  gll16(bG, (char*)Bs[0] + ldsOff);
  gll16(bG + 32 * 512, (char*)Bs[0] + ldsOff + 4096);
  gll16(bG + 64 * 512, (char*)Bs[0] + ldsOff + 8192);
  gll16(bG + 96 * 512, (char*)Bs[0] + ldsOff + 12288);

  for (int kk = 0; kk < 8; kk++) {
    int cur = kk & 1;
    asm volatile("s_waitcnt vmcnt(0)" ::: "memory");   // my tile-kk loads (issued last iter) landed
    __builtin_amdgcn_s_barrier();                      // all waves' loads landed; all done reading buf[cur^1]
    if (kk < 7) {
      int ko = (kk + 1) * 64;
      gll16(aG + ko, (char*)As[cur ^ 1] + ldsOff);
      gll16(aG + ko + 32 * 512, (char*)As[cur ^ 1] + ldsOff + 4096);
      gll16(bG + ko, (char*)Bs[cur ^ 1] + ldsOff);
      gll16(bG + ko + 32 * 512, (char*)Bs[cur ^ 1] + ldsOff + 4096);
      gll16(bG + ko + 64 * 512, (char*)Bs[cur ^ 1] + ldsOff + 8192);
      gll16(bG + ko + 96 * 512, (char*)Bs[cur ^ 1] + ldsOff + 12288);
    }
    bf16x8 af[2][2], bfr[4][2];
#pragma unroll
    for (int kc = 0; kc < 2; kc++) {
#pragma unroll
      for (int mi = 0; mi < 2; mi++)
        af[mi][kc] = *(const bf16x8*)((const char*)As[cur] + ((wr * 2 + mi) * 128 + (kc * 4 + lg) * 16 + c) * 16);
#pragma unroll
      for (int ni = 0; ni < 4; ni++)
        bfr[ni][kc] = *(const bf16x8*)((const char*)Bs[cur] + ((wc * 4 + ni) * 128 + (kc * 4 + lg) * 16 + c) * 16);
    }
#pragma unroll
    for (int kc = 0; kc < 2; kc++)
#pragma unroll
      for (int mi = 0; mi < 2; mi++)
#pragma unroll
        for (int ni = 0; ni < 4; ni++)
          acc[mi][ni] = __builtin_amdgcn_mfma_f32_16x16x32_bf16(af[mi][kc], bfr[ni][kc], acc[mi][ni], 0, 0, 0);
  }

#pragma unroll
  for (int mi = 0; mi < 2; mi++)
#pragma unroll
    for (int ni = 0; ni < 4; ni++) {
      int row = m0 + wr * 32 + mi * 16 + 4 * lg;
      int col = n0 + wc * 64 + ni * 16 + c;
      if constexpr (MODE == 1) {
#pragma unroll
        for (int r = 0; r < 4; r++)
          ((float*)C)[(size_t)(row + r) * 512 + col] = acc[mi][ni][r];
      } else if constexpr (MODE == 0) {
#pragma unroll
        for (int r = 0; r < 4; r++)
          ((unsigned short*)C)[(size_t)(row + r) * 512 + col] = f2bf(acc[mi][ni][r]);
      } else {  // MODE 4
        if (n0 < 512) {
#pragma unroll
          for (int r = 0; r < 4; r++)
            ((unsigned short*)C)[(size_t)(row + r) * 512 + col] = f2bf(acc[mi][ni][r]);
        } else {
          int col5 = col - 512, hd2 = col5 >> 6, vv = col5 & 63;
          int bb = row >> 11, g = row & 2047;
          ushort4 u;
          u.x = f2bf(acc[mi][ni][0]);
          u.y = f2bf(acc[mi][ni][1]);
          u.z = f2bf(acc[mi][ni][2]);
          u.w = f2bf(acc[mi][ni][3]);
          *(ushort4*)((unsigned short*)C2 + (size_t)((bb * 8 + hd2) * 64 + vv) * GS + g) = u;
        }
      }
    }
}

// ---------------- flash attention (swapped-operand, 32 q-rows/wave, counted prefetch) ----------------
// grid 512: fid = (bid&7)*64 + bid>>3 (XCD-bijective). qtile = fid&15 (128 q), bh = fid>>4.
// Qp pre-scaled by 0.125*log2(e) -> P = 2^(S^T).
// Per iter: vmcnt(0) [loads issued one compute-phase ago] -> raw s_barrier -> issue kt+1
// staging + mask prefetch -> QK^T -> exp -> pack P -> PV. One barrier/iter, no fresh-load drain.
__global__ __launch_bounds__(256) void k_attn4(const unsigned short* __restrict__ Qp,
                                               const unsigned short* __restrict__ Kp,
                                               const unsigned short* __restrict__ Vt,
                                               const unsigned long long* __restrict__ maskB,
                                               unsigned short* __restrict__ Hd) {
  __shared__ unsigned short Ksh[2][4096];
  __shared__ unsigned short Vsh[2][4096];
  __shared__ unsigned short Plds[4][2048];

  int bid = blockIdx.x;
  int fid = (bid & 7) * 64 + (bid >> 3);   // bijective XCD swizzle (512 = 8*64)
  int qtile = fid & 15;
  int bh = fid >> 4;
  int b = bh >> 3, hd = bh & 7;

  int t = threadIdx.x;
  int w = t >> 6, l = t & 63, c = l & 15, lg = l >> 4;
  int qw = qtile * 128 + w * 32;

  // Q B-fragments in registers
  bf16x8 qb[2][2];
#pragma unroll
  for (int qt = 0; qt < 2; qt++)
#pragma unroll
    for (int kc = 0; kc < 2; kc++)
      qb[qt][kc] = *(const bf16x8*)(Qp + (size_t)(b * NQS + qw + qt * 16 + c) * 512 + hd * 64 + kc * 32 + lg * 8);

  // staging coords (fragment-linear chunks; verified R4 layout)
  int sr = ((t >> 7) & 1) * 16 + (t & 15);
  int sdc = ((t >> 6) & 1) * 4 + ((t >> 4) & 3);
  const unsigned short* kgbase = Kp + (size_t)(b * GS + sr) * 512 + hd * 64 + sdc * 8;
  const unsigned short* vgbase = Vt + (size_t)(bh * 64 + sr) * GS + sdc * 8;
  char* kdst[2] = {(char*)&Ksh[0][0] + w * 1024, (char*)&Ksh[1][0] + w * 1024};
  char* vdst[2] = {(char*)&Vsh[0][0] + w * 1024, (char*)&Vsh[1][0] + w * 1024};

  f32x4 o[4][2];
#pragma unroll
  for (int vt = 0; vt < 4; vt++) { o[vt][0] = {0.f, 0.f, 0.f, 0.f}; o[vt][1] = {0.f, 0.f, 0.f, 0.f}; }
  float lrow[2] = {0.f, 0.f};

  // prologue: stage tile 0 into buffer 0; preload masks for kt=0
  gll16(kgbase, kdst[0]);
  gll16(kgbase + 32 * 512, kdst[0] + 4096);
  gll16(vgbase, vdst[0]);
  gll16(vgbase + 32 * GS, vdst[0] + 4096);
  const unsigned long long* mbase0 = maskB + (size_t)(b * NQS + qw + c) * 32;
  const unsigned long long* mbase1 = maskB + (size_t)(b * NQS + qw + 16 + c) * 32;
  unsigned long long wm0 = mbase0[0], wm1 = mbase1[0];
  unsigned long long wm0n = 0, wm1n = 0;

  for (int kt = 0; kt < 32; kt++) {
    int cur = kt & 1;
    asm volatile("s_waitcnt vmcnt(0)" ::: "memory");  // tile-kt loads (issued last iter) landed
    __builtin_amdgcn_s_barrier();                     // all waves ready; all done reading buf[cur^1]
    if (kt < 31) {
      size_t g0 = (size_t)(kt + 1) * 64;
      const unsigned short* kg = kgbase + g0 * 512;
      const unsigned short* vg = vgbase + g0;
      char* kd = kdst[cur ^ 1];
      char* vd = vdst[cur ^ 1];
      gll16(kg, kd);
      gll16(kg + 32 * 512, kd + 4096);
      gll16(vg, vd);
      gll16(vg + 32 * GS, vd + 4096);
      wm0n = mbase0[kt + 1];
      wm1n = mbase1[kt + 1];
    }

    // S^T = K * Q^T : s[gt][qt], C layout col=q=l&15, row=g=4*lg+reg
    const unsigned short* Kc = &Ksh[cur][0];
    f32x4 s[4][2];
#pragma unroll
    for (int gt = 0; gt < 4; gt++) { s[gt][0] = {0.f, 0.f, 0.f, 0.f}; s[gt][1] = {0.f, 0.f, 0.f, 0.f}; }
    __builtin_amdgcn_s_setprio(1);
#pragma unroll
    for (int kc = 0; kc < 2; kc++) {
      bf16x8 ka[4];
#pragma unroll
      for (int gt = 0; gt < 4; gt++)
        ka[gt] = *(const bf16x8*)(Kc + ((gt * 2 + kc) * 64 + l) * 8);
#pragma unroll
      for (int gt = 0; gt < 4; gt++) {
        s[gt][0] = __builtin_amdgcn_mfma_f32_16x16x32_bf16(ka[gt], qb[0][kc], s[gt][0], 0, 0, 0);
        s[gt][1] = __builtin_amdgcn_mfma_f32_16x16x32_bf16(ka[gt], qb[1][kc], s[gt][1], 0, 0, 0);
      }
    }
    __builtin_amdgcn_s_setprio(0);

    // masked 2^s (no running max: scores bounded; all-masked rows -> l=0 -> out=0)
#pragma unroll
    for (int qt = 0; qt < 2; qt++) {
      unsigned long long wmq = qt ? wm1 : wm0;
      float ls = 0.f;
#pragma unroll
      for (int gt = 0; gt < 4; gt++) {
        unsigned nib = (unsigned)(wmq >> (gt * 16));
        f32x4 pv;
#pragma unroll
        for (int r = 0; r < 4; r++) {
          float e = EXP2(s[gt][qt][r]);
          unsigned bitm = (nib >> (4 * lg + r)) & 1u;
          pv[r] = bitm ? 0.f : e;
          ls += pv[r];
        }
        s[gt][qt] = pv;
      }
      lrow[qt] += ls;
    }

    // pack P^T (bf16, v_cvt_pk) into per-wave fragment-linear LDS
#pragma unroll
    for (int qt = 0; qt < 2; qt++)
#pragma unroll
      for (int gt = 0; gt < 4; gt++) {
        uint2 wp;
        asm("v_cvt_pk_bf16_f32 %0, %1, %2" : "=v"(wp.x) : "v"(s[gt][qt][0]), "v"(s[gt][qt][1]));
        asm("v_cvt_pk_bf16_f32 %0, %1, %2" : "=v"(wp.y) : "v"(s[gt][qt][2]), "v"(s[gt][qt][3]));
        int chunk = (qt * 2 + (gt >> 1)) * 64 + ((gt & 1) * 2 + (lg >> 1)) * 16 + c;
        *(uint2*)((char*)&Plds[w][0] + chunk * 16 + 8 * (lg & 1)) = wp;
      }
    asm volatile("s_waitcnt lgkmcnt(0)" ::: "memory");
    __builtin_amdgcn_sched_barrier(0);

    // O^T += V^T * P^T
    const unsigned short* Vc = &Vsh[cur][0];
    __builtin_amdgcn_s_setprio(1);
#pragma unroll
    for (int kc2 = 0; kc2 < 2; kc2++) {
      bf16x8 pb[2];
#pragma unroll
      for (int qt = 0; qt < 2; qt++)
        pb[qt] = *(const bf16x8*)((const char*)&Plds[w][0] + ((qt * 2 + kc2) * 64 + l) * 16);
      bf16x8 va[4];
#pragma unroll
      for (int vt = 0; vt < 4; vt++)
        va[vt] = *(const bf16x8*)(Vc + ((vt * 2 + kc2) * 64 + l) * 8);
#pragma unroll
      for (int vt = 0; vt < 4; vt++) {
        o[vt][0] = __builtin_amdgcn_mfma_f32_16x16x32_bf16(va[vt], pb[0], o[vt][0], 0, 0, 0);
        o[vt][1] = __builtin_amdgcn_mfma_f32_16x16x32_bf16(va[vt], pb[1], o[vt][1], 0, 0, 0);
      }
    }
    __builtin_amdgcn_s_setprio(0);
    wm0 = wm0n;
    wm1 = wm1n;
  }

  // epilogue: reduce l across the 4 lanes sharing q, normalize, store
#pragma unroll
  for (int qt = 0; qt < 2; qt++) {
    float lr = lrow[qt];
    lr += __shfl_xor(lr, 16);
    lr += __shfl_xor(lr, 32);
    float inv = lr > 0.f ? 1.0f / lr : 0.f;
    int q = qw + qt * 16 + c;
#pragma unroll
    for (int vt = 0; vt < 4; vt++) {
      ushort4 u;
      u.x = f2bf(o[vt][qt][0] * inv);
      u.y = f2bf(o[vt][qt][1] * inv);
      u.z = f2bf(o[vt][qt][2] * inv);
      u.w = f2bf(o[vt][qt][3] * inv);
      *(ushort4*)(Hd + (size_t)(b * NQS + q) * 512 + hd * 64 + vt * 16 + 4 * lg) = u;
    }
  }
}

// ---------------- launch ----------------

extern "C" void kernel_launch(void* const* d_in, const int* in_sizes, int n_in,
                              void* d_out, int out_size, void* d_ws, size_t ws_size,
                              hipStream_t stream) {
  const float* q = (const float*)d_in[0];
  const float* h = (const float*)d_in[1];
  const void* mask = d_in[2];
  const float* wq = (const float*)d_in[3];
  const float* wk = (const float*)d_in[4];
  const float* wv = (const float*)d_in[5];
  const float* wo = (const float*)d_in[6];
  float* out = (float*)d_out;

  unsigned short* qb_ = (unsigned short*)d_ws;       // 8192*512 each
  unsigned short* hb_ = qb_ + 8192 * 512;
  unsigned short* Qp = hb_ + 8192 * 512;
  unsigned short* Kp = Qp + 8192 * 512;
  unsigned short* Vtp = Kp + 8192 * 512;             // transposed V: [(b*8+h)*64+v][2048]
  unsigned short* Hd = Vtp + 8192 * 512;
  unsigned short* wqt = Hd + 8192 * 512;
  unsigned short* wkvt = wqt + 512 * 512;            // [1024][512]: wk rows 0-511, wv rows 512-1023
  unsigned short* wot = wkvt + 1024 * 512;
  unsigned long long* maskB = (unsigned long long*)(wot + 512 * 512);  // 4*2048*32 u64 = 2 MB
  unsigned int* flag = (unsigned int*)(maskB + (size_t)4 * 2048 * 32);

  k_detect<<<1, 256, 0, stream>>>((const unsigned int*)mask, flag);
  k_cvt2<<<4096, 256, 0, stream>>>((const float4*)q, (const float4*)h, (ushort4*)qb_, (ushort4*)hb_);
  k_pack_all<<<4096, 256, 0, stream>>>(wq, wk, wv, wo, wqt, wkvt, wot);
  k_maskpack<<<65536, 256, 0, stream>>>((const unsigned char*)mask, (const int*)mask, flag, maskB);
  dim3 gq(128, 4);
  k_gemm3<0><<<gq, 256, 0, stream>>>(qb_, wqt, Qp, nullptr);
  dim3 gkv(128, 8);
  k_gemm3<4><<<gkv, 256, 0, stream>>>(hb_, wkvt, Kp, Vtp);
  k_attn4<<<512, 256, 0, stream>>>(Qp, Kp, Vtp, maskB, Hd);
  dim3 go(128, 4);
  k_gemm3<1><<<go, 256, 0, stream>>>(Hd, wot, out, nullptr);
}

// Round 8
// 178.904 us; speedup vs baseline: 1.0658x; 1.0147x over previous
//
#include <hip/hip_runtime.h>
#include <hip/hip_bf16.h>
#include <stdint.h>

#define NHEADS 8
#define INDIM 512
#define EMB 512
#define BSZ 4
#define NQS 2048
#define GS 2048

// 0.125 * log2(e): folded into W_query so attention exp is a bare 2^x
#define ALPHA_F 0.18033688011112042f

#if __has_builtin(__builtin_amdgcn_exp2f)
#define EXP2(x) __builtin_amdgcn_exp2f(x)
#else
#define EXP2(x) __expf((x)*0.69314718056f)
#endif

typedef short bf16x8 __attribute__((ext_vector_type(8)));
typedef float f32x4 __attribute__((ext_vector_type(4)));

static __device__ __forceinline__ unsigned short f2bf(float f) {
  unsigned int u = __builtin_bit_cast(unsigned int, f);
  unsigned int rounding = 0x7FFFu + ((u >> 16) & 1u);
  u += rounding;
  return (unsigned short)(u >> 16);
}

typedef __attribute__((address_space(3))) void lds_void;
typedef __attribute__((address_space(1))) const void gm_void;
static __device__ __forceinline__ void gll16(const void* g, void* s) {
  __builtin_amdgcn_global_load_lds((gm_void*)g, (lds_void*)s, 16, 0, 0);
}

// ---------------- prep kernels ----------------

// both f32->bf16 converts in one launch: blocks [0,2048) -> a, [2048,4096) -> b
__global__ void k_cvt2(const float4* __restrict__ a, const float4* __restrict__ b,
                       ushort4* __restrict__ da, ushort4* __restrict__ db) {
  int half = blockIdx.x >> 11;
  int i = (blockIdx.x & 2047) * blockDim.x + threadIdx.x;
  const float4* src = half ? b : a;
  ushort4* dst = half ? db : da;
  for (; i < 8192 * 512 / 4; i += 2048 * 256) {
    float4 v = src[i];
    ushort4 o;
    o.x = f2bf(v.x); o.y = f2bf(v.y); o.z = f2bf(v.z); o.w = f2bf(v.w);
    dst[i] = o;
  }
}

// all weight packs in one kernel. wqt scaled by ALPHA. wkvt = [wk(512) | wv(512)] rows.
__global__ void k_pack_all(const float* __restrict__ wq, const float* __restrict__ wk,
                           const float* __restrict__ wv, const float* __restrict__ wo,
                           unsigned short* __restrict__ wqt, unsigned short* __restrict__ wkvt,
                           unsigned short* __restrict__ wot) {
  int id = blockIdx.x * blockDim.x + threadIdx.x;
  int which = id >> 18, r = id & 262143;
  int k = r & 511, n = r >> 9;
  int h = n >> 6, j = n & 63;
  if (which == 0) wqt[r] = f2bf(wq[h * 32768 + k * 64 + j] * ALPHA_F);
  else if (which == 1) wkvt[r] = f2bf(wk[h * 32768 + k * 64 + j]);
  else if (which == 2) wkvt[262144 + r] = f2bf(wv[h * 32768 + k * 64 + j]);
  else wot[r] = f2bf(wo[k * 512 + n]);
}

// detect mask dtype: 1 => 1-byte bools, 0 => int32
__global__ void k_detect(const unsigned int* __restrict__ m, unsigned int* __restrict__ flag) {
  __shared__ unsigned int s;
  if (threadIdx.x == 0) s = 0u;
  __syncthreads();
  unsigned int any = 0u;
  for (int i = threadIdx.x; i < 2048; i += blockDim.x) any |= (m[i] > 1u) ? 1u : 0u;
  if (any) atomicOr(&s, 1u);
  __syncthreads();
  if (threadIdx.x == 0) *flag = s;
}

// bit-pack mask: maskB[(b*NQS+q)*32 + g64] bit (g&63) = mask(b,q,g)
__global__ void k_maskpack(const unsigned char* __restrict__ m8, const int* __restrict__ m32,
                           const unsigned int* __restrict__ flag,
                           unsigned long long* __restrict__ mb) {
  size_t i = (size_t)blockIdx.x * blockDim.x + threadIdx.x;
  bool bytes = (*flag != 0u);
  int v = bytes ? (int)m8[i] : m32[i];
  unsigned long long bal = __ballot(v != 0);
  if ((threadIdx.x & 63) == 0) mb[i >> 6] = bal;
}

// ---------------- GEMM3: C[m][n] = sum_k A[m][k]*Bt[n][k]; K=512, bf16 ----------------
// BM=64, BN=128, BK=64, 256 thr, gll16 staging, fragment-linear LDS, counted-prefetch.
// MODE 0: bf16 C. MODE 1: f32 C. MODE 4: N=1024 fused KV (cols>=512 -> transposed C2).

template <int MODE>
__global__ __launch_bounds__(256) void k_gemm3(const unsigned short* __restrict__ A,
                                               const unsigned short* __restrict__ Bt,
                                               void* __restrict__ C, void* __restrict__ C2) {
  __shared__ unsigned short As[2][4096];   // 64 x 64
  __shared__ unsigned short Bs[2][8192];   // 128 x 64
  int m0 = blockIdx.x * 64, n0 = blockIdx.y * 128;
  int t = threadIdx.x;
  int w = t >> 6, l = t & 63, c = l & 15, lg = l >> 4;
  int wr = w >> 1, wc = w & 1;

  int rbA = t >> 7, kcc = (t >> 4) & 7, cc = t & 15;
  const unsigned short* aG = A + (size_t)(m0 + rbA * 16 + cc) * 512 + kcc * 8;
  const unsigned short* bG = Bt + (size_t)(n0 + rbA * 16 + cc) * 512 + kcc * 8;
  int ldsOff = w * 1024 + (t & 63) * 16;

  f32x4 acc[2][4];
#pragma unroll
  for (int mi = 0; mi < 2; mi++)
#pragma unroll
    for (int ni = 0; ni < 4; ni++) acc[mi][ni] = {0.f, 0.f, 0.f, 0.f};

  gll16(aG, (char*)As[0] + ldsOff);
  gll16(aG + 32 * 512, (char*)As[0] + ldsOff + 4096);
  gll16(bG, (char*)Bs[0] + ldsOff);
  gll16(bG + 32 * 512, (char*)Bs[0] + ldsOff + 4096);
  gll16(bG + 64 * 512, (char*)Bs[0] + ldsOff + 8192);
  gll16(bG + 96 * 512, (char*)Bs[0] + ldsOff + 12288);

  for (int kk = 0; kk < 8; kk++) {
    int cur = kk & 1;
    asm volatile("s_waitcnt vmcnt(0)" ::: "memory");
    __builtin_amdgcn_s_barrier();
    if (kk < 7) {
      int ko = (kk + 1) * 64;
      gll16(aG + ko, (char*)As[cur ^ 1] + ldsOff);
      gll16(aG + ko + 32 * 512, (char*)As[cur ^ 1] + ldsOff + 4096);
      gll16(bG + ko, (char*)Bs[cur ^ 1] + ldsOff);
      gll16(bG + ko + 32 * 512, (char*)Bs[cur ^ 1] + ldsOff + 4096);
      gll16(bG + ko + 64 * 512, (char*)Bs[cur ^ 1] + ldsOff + 8192);
      gll16(bG + ko + 96 * 512, (char*)Bs[cur ^ 1] + ldsOff + 12288);
    }
    bf16x8 af[2][2], bfr[4][2];
#pragma unroll
    for (int kc = 0; kc < 2; kc++) {
#pragma unroll
      for (int mi = 0; mi < 2; mi++)
        af[mi][kc] = *(const bf16x8*)((const char*)As[cur] + ((wr * 2 + mi) * 128 + (kc * 4 + lg) * 16 + c) * 16);
#pragma unroll
      for (int ni = 0; ni < 4; ni++)
        bfr[ni][kc] = *(const bf16x8*)((const char*)Bs[cur] + ((wc * 4 + ni) * 128 + (kc * 4 + lg) * 16 + c) * 16);
    }
#pragma unroll
    for (int kc = 0; kc < 2; kc++)
#pragma unroll
      for (int mi = 0; mi < 2; mi++)
#pragma unroll
        for (int ni = 0; ni < 4; ni++)
          acc[mi][ni] = __builtin_amdgcn_mfma_f32_16x16x32_bf16(af[mi][kc], bfr[ni][kc], acc[mi][ni], 0, 0, 0);
  }

#pragma unroll
  for (int mi = 0; mi < 2; mi++)
#pragma unroll
    for (int ni = 0; ni < 4; ni++) {
      int row = m0 + wr * 32 + mi * 16 + 4 * lg;
      int col = n0 + wc * 64 + ni * 16 + c;
      if constexpr (MODE == 1) {
#pragma unroll
        for (int r = 0; r < 4; r++)
          ((float*)C)[(size_t)(row + r) * 512 + col] = acc[mi][ni][r];
      } else if constexpr (MODE == 0) {
#pragma unroll
        for (int r = 0; r < 4; r++)
          ((unsigned short*)C)[(size_t)(row + r) * 512 + col] = f2bf(acc[mi][ni][r]);
      } else {  // MODE 4
        if (n0 < 512) {
#pragma unroll
          for (int r = 0; r < 4; r++)
            ((unsigned short*)C)[(size_t)(row + r) * 512 + col] = f2bf(acc[mi][ni][r]);
        } else {
          int col5 = col - 512, hd2 = col5 >> 6, vv = col5 & 63;
          int bb = row >> 11, g = row & 2047;
          ushort4 u;
          u.x = f2bf(acc[mi][ni][0]);
          u.y = f2bf(acc[mi][ni][1]);
          u.z = f2bf(acc[mi][ni][2]);
          u.w = f2bf(acc[mi][ni][3]);
          *(ushort4*)((unsigned short*)C2 + (size_t)((bb * 8 + hd2) * 64 + vv) * GS + g) = u;
        }
      }
    }
}

// ---------------- flash attention: KVBLK=128 (2x verified 64-g halves per barrier) ----------------
// grid 512: fid = (bid&7)*64 + bid>>3 (XCD-bijective). qtile = fid&15 (128 q), bh = fid>>4.
// Qp pre-scaled by 0.125*log2(e) -> P = 2^(S^T). 16 outer iters; one vmcnt(0)+s_barrier per iter.
__global__ __launch_bounds__(256) void k_attn5(const unsigned short* __restrict__ Qp,
                                               const unsigned short* __restrict__ Kp,
                                               const unsigned short* __restrict__ Vt,
                                               const unsigned long long* __restrict__ maskB,
                                               unsigned short* __restrict__ Hd) {
  __shared__ unsigned short Ksh[2][8192];   // 2 bufs x (128g x 64d), two fragment-linear 64-g halves
  __shared__ unsigned short Vsh[2][8192];   // 2 bufs x (64v x 128g), two fragment-linear 64-g halves
  __shared__ unsigned short Plds[4][2048];  // per-wave P tile (32q x 64g)

  int bid = blockIdx.x;
  int fid = (bid & 7) * 64 + (bid >> 3);
  int qtile = fid & 15;
  int bh = fid >> 4;
  int b = bh >> 3, hd = bh & 7;

  int t = threadIdx.x;
  int w = t >> 6, l = t & 63, c = l & 15, lg = l >> 4;
  int qw = qtile * 128 + w * 32;

  // Q B-fragments in registers
  bf16x8 qb[2][2];
#pragma unroll
  for (int qt = 0; qt < 2; qt++)
#pragma unroll
    for (int kc = 0; kc < 2; kc++)
      qb[qt][kc] = *(const bf16x8*)(Qp + (size_t)(b * NQS + qw + qt * 16 + c) * 512 + hd * 64 + kc * 32 + lg * 8);

  // staging coords (fragment-linear chunks; verified R4 layout, replicated per 64-g half)
  int sr = ((t >> 7) & 1) * 16 + (t & 15);
  int sdc = ((t >> 6) & 1) * 4 + ((t >> 4) & 3);
  const unsigned short* kgbase = Kp + (size_t)(b * GS + sr) * 512 + hd * 64 + sdc * 8;
  const unsigned short* vgbase = Vt + (size_t)(bh * 64 + sr) * GS + sdc * 8;
  char* kdst[2] = {(char*)&Ksh[0][0] + w * 1024, (char*)&Ksh[1][0] + w * 1024};
  char* vdst[2] = {(char*)&Vsh[0][0] + w * 1024, (char*)&Vsh[1][0] + w * 1024};

  f32x4 o[4][2];
#pragma unroll
  for (int vt = 0; vt < 4; vt++) { o[vt][0] = {0.f, 0.f, 0.f, 0.f}; o[vt][1] = {0.f, 0.f, 0.f, 0.f}; }
  float lrow[2] = {0.f, 0.f};

  const unsigned long long* mbase0 = maskB + (size_t)(b * NQS + qw + c) * 32;
  const unsigned long long* mbase1 = maskB + (size_t)(b * NQS + qw + 16 + c) * 32;

  // prologue: stage tile 0 (128 g) into buffer 0; preload its 4 masks
#pragma unroll
  for (int hh = 0; hh < 2; hh++) {
    const unsigned short* kg = kgbase + (size_t)(hh * 64) * 512;
    const unsigned short* vg = vgbase + hh * 64;
    gll16(kg, kdst[0] + hh * 8192);
    gll16(kg + 32 * 512, kdst[0] + hh * 8192 + 4096);
    gll16(vg, vdst[0] + hh * 8192);
    gll16(vg + 32 * GS, vdst[0] + hh * 8192 + 4096);
  }
  unsigned long long wm[2][2], wmn[2][2];
  wm[0][0] = mbase0[0]; wm[0][1] = mbase0[1];
  wm[1][0] = mbase1[0]; wm[1][1] = mbase1[1];

  for (int kt = 0; kt < 16; kt++) {
    int cur = kt & 1;
    asm volatile("s_waitcnt vmcnt(0)" ::: "memory");  // tile-kt loads (issued last iter) landed
    __builtin_amdgcn_s_barrier();                     // all waves ready; all done reading buf[cur^1]
    if (kt < 15) {
      size_t g0 = (size_t)(kt + 1) * 128;
#pragma unroll
      for (int hh = 0; hh < 2; hh++) {
        const unsigned short* kg = kgbase + (g0 + hh * 64) * 512;
        const unsigned short* vg = vgbase + g0 + hh * 64;
        char* kd = kdst[cur ^ 1] + hh * 8192;
        char* vd = vdst[cur ^ 1] + hh * 8192;
        gll16(kg, kd);
        gll16(kg + 32 * 512, kd + 4096);
        gll16(vg, vd);
        gll16(vg + 32 * GS, vd + 4096);
      }
      wmn[0][0] = mbase0[(kt + 1) * 2]; wmn[0][1] = mbase0[(kt + 1) * 2 + 1];
      wmn[1][0] = mbase1[(kt + 1) * 2]; wmn[1][1] = mbase1[(kt + 1) * 2 + 1];
    }

#pragma unroll
    for (int hh = 0; hh < 2; hh++) {
      // S^T = K * Q^T : s[gt][qt], C layout col=q=l&15, row=g=4*lg+reg
      const unsigned short* Kc = &Ksh[cur][hh * 4096];
      f32x4 s[4][2];
#pragma unroll
      for (int gt = 0; gt < 4; gt++) { s[gt][0] = {0.f, 0.f, 0.f, 0.f}; s[gt][1] = {0.f, 0.f, 0.f, 0.f}; }
      __builtin_amdgcn_s_setprio(1);
#pragma unroll
      for (int kc = 0; kc < 2; kc++) {
        bf16x8 ka[4];
#pragma unroll
        for (int gt = 0; gt < 4; gt++)
          ka[gt] = *(const bf16x8*)(Kc + ((gt * 2 + kc) * 64 + l) * 8);
#pragma unroll
        for (int gt = 0; gt < 4; gt++) {
          s[gt][0] = __builtin_amdgcn_mfma_f32_16x16x32_bf16(ka[gt], qb[0][kc], s[gt][0], 0, 0, 0);
          s[gt][1] = __builtin_amdgcn_mfma_f32_16x16x32_bf16(ka[gt], qb[1][kc], s[gt][1], 0, 0, 0);
        }
      }
      __builtin_amdgcn_s_setprio(0);

      // masked 2^s (no running max: scores bounded; all-masked rows -> l=0 -> out=0)
#pragma unroll
      for (int qt = 0; qt < 2; qt++) {
        unsigned long long wmq = wm[qt][hh];
        float ls = 0.f;
#pragma unroll
        for (int gt = 0; gt < 4; gt++) {
          unsigned nib = (unsigned)(wmq >> (gt * 16));
          f32x4 pv;
#pragma unroll
          for (int r = 0; r < 4; r++) {
            float e = EXP2(s[gt][qt][r]);
            unsigned bitm = (nib >> (4 * lg + r)) & 1u;
            pv[r] = bitm ? 0.f : e;
            ls += pv[r];
          }
          s[gt][qt] = pv;
        }
        lrow[qt] += ls;
      }

      // pack P^T (bf16, v_cvt_pk) into per-wave fragment-linear LDS
#pragma unroll
      for (int qt = 0; qt < 2; qt++)
#pragma unroll
        for (int gt = 0; gt < 4; gt++) {
          uint2 wp;
          asm("v_cvt_pk_bf16_f32 %0, %1, %2" : "=v"(wp.x) : "v"(s[gt][qt][0]), "v"(s[gt][qt][1]));
          asm("v_cvt_pk_bf16_f32 %0, %1, %2" : "=v"(wp.y) : "v"(s[gt][qt][2]), "v"(s[gt][qt][3]));
          int chunk = (qt * 2 + (gt >> 1)) * 64 + ((gt & 1) * 2 + (lg >> 1)) * 16 + c;
          *(uint2*)((char*)&Plds[w][0] + chunk * 16 + 8 * (lg & 1)) = wp;
        }
      asm volatile("s_waitcnt lgkmcnt(0)" ::: "memory");
      __builtin_amdgcn_sched_barrier(0);

      // O^T += V^T * P^T
      const unsigned short* Vc = &Vsh[cur][hh * 4096];
      __builtin_amdgcn_s_setprio(1);
#pragma unroll
      for (int kc2 = 0; kc2 < 2; kc2++) {
        bf16x8 pb[2];
#pragma unroll
        for (int qt = 0; qt < 2; qt++)
          pb[qt] = *(const bf16x8*)((const char*)&Plds[w][0] + ((qt * 2 + kc2) * 64 + l) * 16);
        bf16x8 va[4];
#pragma unroll
        for (int vt = 0; vt < 4; vt++)
          va[vt] = *(const bf16x8*)(Vc + ((vt * 2 + kc2) * 64 + l) * 8);
#pragma unroll
        for (int vt = 0; vt < 4; vt++) {
          o[vt][0] = __builtin_amdgcn_mfma_f32_16x16x32_bf16(va[vt], pb[0], o[vt][0], 0, 0, 0);
          o[vt][1] = __builtin_amdgcn_mfma_f32_16x16x32_bf16(va[vt], pb[1], o[vt][1], 0, 0, 0);
        }
      }
      __builtin_amdgcn_s_setprio(0);
    }
    wm[0][0] = wmn[0][0]; wm[0][1] = wmn[0][1];
    wm[1][0] = wmn[1][0]; wm[1][1] = wmn[1][1];
  }

  // epilogue: reduce l across the 4 lanes sharing q, normalize, store
#pragma unroll
  for (int qt = 0; qt < 2; qt++) {
    float lr = lrow[qt];
    lr += __shfl_xor(lr, 16);
    lr += __shfl_xor(lr, 32);
    float inv = lr > 0.f ? 1.0f / lr : 0.f;
    int q = qw + qt * 16 + c;
#pragma unroll
    for (int vt = 0; vt < 4; vt++) {
      ushort4 u;
      u.x = f2bf(o[vt][qt][0] * inv);
      u.y = f2bf(o[vt][qt][1] * inv);
      u.z = f2bf(o[vt][qt][2] * inv);
      u.w = f2bf(o[vt][qt][3] * inv);
      *(ushort4*)(Hd + (size_t)(b * NQS + q) * 512 + hd * 64 + vt * 16 + 4 * lg) = u;
    }
  }
}

// ---------------- launch ----------------

extern "C" void kernel_launch(void* const* d_in, const int* in_sizes, int n_in,
                              void* d_out, int out_size, void* d_ws, size_t ws_size,
                              hipStream_t stream) {
  const float* q = (const float*)d_in[0];
  const float* h = (const float*)d_in[1];
  const void* mask = d_in[2];
  const float* wq = (const float*)d_in[3];
  const float* wk = (const float*)d_in[4];
  const float* wv = (const float*)d_in[5];
  const float* wo = (const float*)d_in[6];
  float* out = (float*)d_out;

  unsigned short* qb_ = (unsigned short*)d_ws;       // 8192*512 each
  unsigned short* hb_ = qb_ + 8192 * 512;
  unsigned short* Qp = hb_ + 8192 * 512;
  unsigned short* Kp = Qp + 8192 * 512;
  unsigned short* Vtp = Kp + 8192 * 512;             // transposed V: [(b*8+h)*64+v][2048]
  unsigned short* Hd = Vtp + 8192 * 512;
  unsigned short* wqt = Hd + 8192 * 512;
  unsigned short* wkvt = wqt + 512 * 512;            // [1024][512]: wk rows 0-511, wv rows 512-1023
  unsigned short* wot = wkvt + 1024 * 512;
  unsigned long long* maskB = (unsigned long long*)(wot + 512 * 512);  // 4*2048*32 u64 = 2 MB
  unsigned int* flag = (unsigned int*)(maskB + (size_t)4 * 2048 * 32);

  k_detect<<<1, 256, 0, stream>>>((const unsigned int*)mask, flag);
  k_cvt2<<<4096, 256, 0, stream>>>((const float4*)q, (const float4*)h, (ushort4*)qb_, (ushort4*)hb_);
  k_pack_all<<<4096, 256, 0, stream>>>(wq, wk, wv, wo, wqt, wkvt, wot);
  k_maskpack<<<65536, 256, 0, stream>>>((const unsigned char*)mask, (const int*)mask, flag, maskB);
  dim3 gq(128, 4);
  k_gemm3<0><<<gq, 256, 0, stream>>>(qb_, wqt, Qp, nullptr);
  dim3 gkv(128, 8);
  k_gemm3<4><<<gkv, 256, 0, stream>>>(hb_, wkvt, Kp, Vtp);
  k_attn5<<<512, 256, 0, stream>>>(Qp, Kp, Vtp, maskB, Hd);
  dim3 go(128, 4);
  k_gemm3<1><<<go, 256, 0, stream>>>(Hd, wot, out, nullptr);
}

// Round 9
// 145.329 us; speedup vs baseline: 1.3121x; 1.2310x over previous
//
#include <hip/hip_runtime.h>
#include <hip/hip_bf16.h>
#include <stdint.h>

#define NHEADS 8
#define INDIM 512
#define EMB 512
#define BSZ 4
#define NQS 2048
#define GS 2048

// 0.125 * log2(e): folded into W_query so attention exp is a bare 2^x
#define ALPHA_F 0.18033688011112042f

#if __has_builtin(__builtin_amdgcn_exp2f)
#define EXP2(x) __builtin_amdgcn_exp2f(x)
#else
#define EXP2(x) __expf((x)*0.69314718056f)
#endif

typedef short bf16x8 __attribute__((ext_vector_type(8)));
typedef float f32x4 __attribute__((ext_vector_type(4)));

static __device__ __forceinline__ unsigned short f2bf(float f) {
  unsigned int u = __builtin_bit_cast(unsigned int, f);
  unsigned int rounding = 0x7FFFu + ((u >> 16) & 1u);
  u += rounding;
  return (unsigned short)(u >> 16);
}

typedef __attribute__((address_space(3))) void lds_void;
typedef __attribute__((address_space(1))) const void gm_void;
static __device__ __forceinline__ void gll16(const void* g, void* s) {
  __builtin_amdgcn_global_load_lds((gm_void*)g, (lds_void*)s, 16, 0, 0);
}

// ---------------- fused prep: cvt q,h + pack weights + bit-pack mask ----------------
// grid 3584 x 256:
//   [0,1024):   q f32->bf16 (262144 thr x 4 float4)
//   [1024,2048): h f32->bf16
//   [2048,3072): mask -> u16 bit-words (16 g per u16), inline dtype detect
//   [3072,3584): weight packs (131072 thr x 8 elems)
__global__ void k_prep(const float4* __restrict__ q, const float4* __restrict__ h,
                       const void* __restrict__ mask,
                       const float* __restrict__ wq, const float* __restrict__ wk,
                       const float* __restrict__ wv, const float* __restrict__ wo,
                       ushort4* __restrict__ qb, ushort4* __restrict__ hb,
                       unsigned short* __restrict__ wqt, unsigned short* __restrict__ wkvt,
                       unsigned short* __restrict__ wot, unsigned short* __restrict__ maskB16) {
  int blk = blockIdx.x, t = threadIdx.x;
  if (blk < 2048) {
    const float4* src = blk < 1024 ? q : h;
    ushort4* dst = blk < 1024 ? qb : hb;
    int base = (blk & 1023) * 256 + t;
#pragma unroll
    for (int i = 0; i < 4; i++) {
      int idx = base + i * 262144;
      float4 v = src[idx];
      ushort4 o;
      o.x = f2bf(v.x); o.y = f2bf(v.y); o.z = f2bf(v.z); o.w = f2bf(v.w);
      dst[idx] = o;
    }
  } else if (blk < 3072) {
    // detect dtype (wave-uniform): int32 0/1 words are never >1; packed bools are
    const unsigned int* m32h = (const unsigned int*)mask;
    bool bytes = __ballot(m32h[t & 63] > 1u) != 0ull;
    int base = (blk - 2048) * 256 + t;   // u16 writer id, 0..262143
#pragma unroll
    for (int i = 0; i < 4; i++) {
      int widx = base + i * 262144;      // covers g-range [widx*16, widx*16+16)
      unsigned int bits = 0;
      if (bytes) {
        const uchar4* p = (const uchar4*)((const unsigned char*)mask + (size_t)widx * 16);
#pragma unroll
        for (int j = 0; j < 4; j++) {
          uchar4 v = p[j];
          bits |= ((v.x ? 1u : 0u) << (4 * j)) | ((v.y ? 1u : 0u) << (4 * j + 1)) |
                  ((v.z ? 1u : 0u) << (4 * j + 2)) | ((v.w ? 1u : 0u) << (4 * j + 3));
        }
      } else {
        const int4* p = (const int4*)((const int*)mask + (size_t)widx * 16);
#pragma unroll
        for (int j = 0; j < 4; j++) {
          int4 v = p[j];
          bits |= ((v.x ? 1u : 0u) << (4 * j)) | ((v.y ? 1u : 0u) << (4 * j + 1)) |
                  ((v.z ? 1u : 0u) << (4 * j + 2)) | ((v.w ? 1u : 0u) << (4 * j + 3));
        }
      }
      maskB16[widx] = (unsigned short)bits;
    }
  } else {
    int id = (blk - 3072) * 256 + t;     // 0..131071
#pragma unroll
    for (int i = 0; i < 8; i++) {
      int e = id * 8 + i;
      int which = e >> 18, r = e & 262143;
      int k = r & 511, n = r >> 9;
      int hh = n >> 6, j = n & 63;
      if (which == 0) wqt[r] = f2bf(wq[hh * 32768 + k * 64 + j] * ALPHA_F);
      else if (which == 1) wkvt[r] = f2bf(wk[hh * 32768 + k * 64 + j]);
      else if (which == 2) wkvt[262144 + r] = f2bf(wv[hh * 32768 + k * 64 + j]);
      else wot[r] = f2bf(wo[k * 512 + n]);
    }
  }
}

// ---------------- GEMM body (BM=64, BN=128, BK=64, counted prefetch) ----------------
// Writes acc to one of: bf16 C[m][n], f32 C[m][n], or transposed per-head Vt.

template <int MODE>  // 1: f32 C (out proj)
__global__ __launch_bounds__(256) void k_gemm3(const unsigned short* __restrict__ A,
                                               const unsigned short* __restrict__ Bt,
                                               void* __restrict__ C, void* __restrict__ C2) {
  __shared__ unsigned short As[2][4096];
  __shared__ unsigned short Bs[2][8192];
  int m0 = blockIdx.x * 64, n0 = blockIdx.y * 128;
  int t = threadIdx.x;
  int w = t >> 6, l = t & 63, c = l & 15, lg = l >> 4;
  int wr = w >> 1, wc = w & 1;

  int rbA = t >> 7, kcc = (t >> 4) & 7, cc = t & 15;
  const unsigned short* aG = A + (size_t)(m0 + rbA * 16 + cc) * 512 + kcc * 8;
  const unsigned short* bG = Bt + (size_t)(n0 + rbA * 16 + cc) * 512 + kcc * 8;
  int ldsOff = w * 1024 + (t & 63) * 16;

  f32x4 acc[2][4];
#pragma unroll
  for (int mi = 0; mi < 2; mi++)
#pragma unroll
    for (int ni = 0; ni < 4; ni++) acc[mi][ni] = {0.f, 0.f, 0.f, 0.f};

  gll16(aG, (char*)As[0] + ldsOff);
  gll16(aG + 32 * 512, (char*)As[0] + ldsOff + 4096);
  gll16(bG, (char*)Bs[0] + ldsOff);
  gll16(bG + 32 * 512, (char*)Bs[0] + ldsOff + 4096);
  gll16(bG + 64 * 512, (char*)Bs[0] + ldsOff + 8192);
  gll16(bG + 96 * 512, (char*)Bs[0] + ldsOff + 12288);

  for (int kk = 0; kk < 8; kk++) {
    int cur = kk & 1;
    asm volatile("s_waitcnt vmcnt(0)" ::: "memory");
    __builtin_amdgcn_s_barrier();
    if (kk < 7) {
      int ko = (kk + 1) * 64;
      gll16(aG + ko, (char*)As[cur ^ 1] + ldsOff);
      gll16(aG + ko + 32 * 512, (char*)As[cur ^ 1] + ldsOff + 4096);
      gll16(bG + ko, (char*)Bs[cur ^ 1] + ldsOff);
      gll16(bG + ko + 32 * 512, (char*)Bs[cur ^ 1] + ldsOff + 4096);
      gll16(bG + ko + 64 * 512, (char*)Bs[cur ^ 1] + ldsOff + 8192);
      gll16(bG + ko + 96 * 512, (char*)Bs[cur ^ 1] + ldsOff + 12288);
    }
    bf16x8 af[2][2], bfr[4][2];
#pragma unroll
    for (int kc = 0; kc < 2; kc++) {
#pragma unroll
      for (int mi = 0; mi < 2; mi++)
        af[mi][kc] = *(const bf16x8*)((const char*)As[cur] + ((wr * 2 + mi) * 128 + (kc * 4 + lg) * 16 + c) * 16);
#pragma unroll
      for (int ni = 0; ni < 4; ni++)
        bfr[ni][kc] = *(const bf16x8*)((const char*)Bs[cur] + ((wc * 4 + ni) * 128 + (kc * 4 + lg) * 16 + c) * 16);
    }
#pragma unroll
    for (int kc = 0; kc < 2; kc++)
#pragma unroll
      for (int mi = 0; mi < 2; mi++)
#pragma unroll
        for (int ni = 0; ni < 4; ni++)
          acc[mi][ni] = __builtin_amdgcn_mfma_f32_16x16x32_bf16(af[mi][kc], bfr[ni][kc], acc[mi][ni], 0, 0, 0);
  }

#pragma unroll
  for (int mi = 0; mi < 2; mi++)
#pragma unroll
    for (int ni = 0; ni < 4; ni++) {
      int row = m0 + wr * 32 + mi * 16 + 4 * lg;
      int col = n0 + wc * 64 + ni * 16 + c;
#pragma unroll
      for (int r = 0; r < 4; r++)
        ((float*)C)[(size_t)(row + r) * 512 + col] = acc[mi][ni][r];
    }
}

// fused Q/K/V projection: grid (128, 12). y<4: Q proj -> Qp bf16.
// y in [4,8): K proj -> Kp bf16. y in [8,12): V proj -> transposed Vt.
__global__ __launch_bounds__(256) void k_gemmQKV(const unsigned short* __restrict__ qb_,
                                                 const unsigned short* __restrict__ hb_,
                                                 const unsigned short* __restrict__ wqt,
                                                 const unsigned short* __restrict__ wkvt,
                                                 unsigned short* __restrict__ Qp,
                                                 unsigned short* __restrict__ Kp,
                                                 unsigned short* __restrict__ Vt) {
  __shared__ unsigned short As[2][4096];
  __shared__ unsigned short Bs[2][8192];
  int ny = blockIdx.y;
  const unsigned short* A = (ny < 4) ? qb_ : hb_;
  const unsigned short* Bt = (ny < 4) ? wqt : wkvt;
  int n0 = (ny < 4) ? ny * 128 : (ny - 4) * 128;   // for KV: 0..1023 into wkvt rows
  int m0 = blockIdx.x * 64;
  int t = threadIdx.x;
  int w = t >> 6, l = t & 63, c = l & 15, lg = l >> 4;
  int wr = w >> 1, wc = w & 1;

  int rbA = t >> 7, kcc = (t >> 4) & 7, cc = t & 15;
  const unsigned short* aG = A + (size_t)(m0 + rbA * 16 + cc) * 512 + kcc * 8;
  const unsigned short* bG = Bt + (size_t)(n0 + rbA * 16 + cc) * 512 + kcc * 8;
  int ldsOff = w * 1024 + (t & 63) * 16;

  f32x4 acc[2][4];
#pragma unroll
  for (int mi = 0; mi < 2; mi++)
#pragma unroll
    for (int ni = 0; ni < 4; ni++) acc[mi][ni] = {0.f, 0.f, 0.f, 0.f};

  gll16(aG, (char*)As[0] + ldsOff);
  gll16(aG + 32 * 512, (char*)As[0] + ldsOff + 4096);
  gll16(bG, (char*)Bs[0] + ldsOff);
  gll16(bG + 32 * 512, (char*)Bs[0] + ldsOff + 4096);
  gll16(bG + 64 * 512, (char*)Bs[0] + ldsOff + 8192);
  gll16(bG + 96 * 512, (char*)Bs[0] + ldsOff + 12288);

  for (int kk = 0; kk < 8; kk++) {
    int cur = kk & 1;
    asm volatile("s_waitcnt vmcnt(0)" ::: "memory");
    __builtin_amdgcn_s_barrier();
    if (kk < 7) {
      int ko = (kk + 1) * 64;
      gll16(aG + ko, (char*)As[cur ^ 1] + ldsOff);
      gll16(aG + ko + 32 * 512, (char*)As[cur ^ 1] + ldsOff + 4096);
      gll16(bG + ko, (char*)Bs[cur ^ 1] + ldsOff);
      gll16(bG + ko + 32 * 512, (char*)Bs[cur ^ 1] + ldsOff + 4096);
      gll16(bG + ko + 64 * 512, (char*)Bs[cur ^ 1] + ldsOff + 8192);
      gll16(bG + ko + 96 * 512, (char*)Bs[cur ^ 1] + ldsOff + 12288);
    }
    bf16x8 af[2][2], bfr[4][2];
#pragma unroll
    for (int kc = 0; kc < 2; kc++) {
#pragma unroll
      for (int mi = 0; mi < 2; mi++)
        af[mi][kc] = *(const bf16x8*)((const char*)As[cur] + ((wr * 2 + mi) * 128 + (kc * 4 + lg) * 16 + c) * 16);
#pragma unroll
      for (int ni = 0; ni < 4; ni++)
        bfr[ni][kc] = *(const bf16x8*)((const char*)Bs[cur] + ((wc * 4 + ni) * 128 + (kc * 4 + lg) * 16 + c) * 16);
    }
#pragma unroll
    for (int kc = 0; kc < 2; kc++)
#pragma unroll
      for (int mi = 0; mi < 2; mi++)
#pragma unroll
        for (int ni = 0; ni < 4; ni++)
          acc[mi][ni] = __builtin_amdgcn_mfma_f32_16x16x32_bf16(af[mi][kc], bfr[ni][kc], acc[mi][ni], 0, 0, 0);
  }

#pragma unroll
  for (int mi = 0; mi < 2; mi++)
#pragma unroll
    for (int ni = 0; ni < 4; ni++) {
      int row = m0 + wr * 32 + mi * 16 + 4 * lg;
      int col = n0 + wc * 64 + ni * 16 + c;
      if (ny < 4) {
#pragma unroll
        for (int r = 0; r < 4; r++)
          Qp[(size_t)(row + r) * 512 + col] = f2bf(acc[mi][ni][r]);
      } else if (col < 512) {
#pragma unroll
        for (int r = 0; r < 4; r++)
          Kp[(size_t)(row + r) * 512 + col] = f2bf(acc[mi][ni][r]);
      } else {
        int col5 = col - 512, hd2 = col5 >> 6, vv = col5 & 63;
        int bb = row >> 11, g = row & 2047;
        ushort4 u;
        u.x = f2bf(acc[mi][ni][0]);
        u.y = f2bf(acc[mi][ni][1]);
        u.z = f2bf(acc[mi][ni][2]);
        u.w = f2bf(acc[mi][ni][3]);
        *(ushort4*)(Vt + (size_t)((bb * 8 + hd2) * 64 + vv) * GS + g) = u;
      }
    }
}

// ---------------- flash attention: KVBLK=128, h0/h1 software pipeline ----------------
// grid 512: fid = (bid&7)*64 + bid>>3. qtile = fid&15 (128 q), bh = fid>>4.
// Qp pre-scaled by 0.125*log2(e) -> P = 2^(S^T).
// Per iter: vmcnt(0) -> s_barrier -> stage kt+1 -> QKT(h0)+QKT(h1) -> sm(h0) -> pack(h0)
// -> sm(h1) -> lgkm -> PV(h0) -> pack(h1) -> lgkm -> PV(h1).
__global__ __launch_bounds__(256) void k_attn6(const unsigned short* __restrict__ Qp,
                                               const unsigned short* __restrict__ Kp,
                                               const unsigned short* __restrict__ Vt,
                                               const unsigned short* __restrict__ maskB16,
                                               unsigned short* __restrict__ Hd) {
  __shared__ unsigned short Ksh[2][8192];
  __shared__ unsigned short Vsh[2][8192];
  __shared__ unsigned short Plds[4][2048];

  int bid = blockIdx.x;
  int fid = (bid & 7) * 64 + (bid >> 3);
  int qtile = fid & 15;
  int bh = fid >> 4;
  int b = bh >> 3, hd = bh & 7;

  int t = threadIdx.x;
  int w = t >> 6, l = t & 63, c = l & 15, lg = l >> 4;
  int qw = qtile * 128 + w * 32;

  bf16x8 qb[2][2];
#pragma unroll
  for (int qt = 0; qt < 2; qt++)
#pragma unroll
    for (int kc = 0; kc < 2; kc++)
      qb[qt][kc] = *(const bf16x8*)(Qp + (size_t)(b * NQS + qw + qt * 16 + c) * 512 + hd * 64 + kc * 32 + lg * 8);

  int sr = ((t >> 7) & 1) * 16 + (t & 15);
  int sdc = ((t >> 6) & 1) * 4 + ((t >> 4) & 3);
  const unsigned short* kgbase = Kp + (size_t)(b * GS + sr) * 512 + hd * 64 + sdc * 8;
  const unsigned short* vgbase = Vt + (size_t)(bh * 64 + sr) * GS + sdc * 8;
  char* kdst[2] = {(char*)&Ksh[0][0] + w * 1024, (char*)&Ksh[1][0] + w * 1024};
  char* vdst[2] = {(char*)&Vsh[0][0] + w * 1024, (char*)&Vsh[1][0] + w * 1024};

  f32x4 o[4][2];
#pragma unroll
  for (int vt = 0; vt < 4; vt++) { o[vt][0] = {0.f, 0.f, 0.f, 0.f}; o[vt][1] = {0.f, 0.f, 0.f, 0.f}; }
  float lrow[2] = {0.f, 0.f};

  // mask pointers: one ulonglong2 per (q-group, 128-g tile); .x = h0 bits, .y = h1 bits
  const ulonglong2* mp0 = (const ulonglong2*)(maskB16 + (size_t)(b * NQS + qw + c) * 128);
  const ulonglong2* mp1 = (const ulonglong2*)(maskB16 + (size_t)(b * NQS + qw + 16 + c) * 128);

  // prologue: stage tile 0 (128 g) into buffer 0
#pragma unroll
  for (int hh = 0; hh < 2; hh++) {
    const unsigned short* kg = kgbase + (size_t)(hh * 64) * 512;
    const unsigned short* vg = vgbase + hh * 64;
    gll16(kg, kdst[0] + hh * 8192);
    gll16(kg + 32 * 512, kdst[0] + hh * 8192 + 4096);
    gll16(vg, vdst[0] + hh * 8192);
    gll16(vg + 32 * GS, vdst[0] + hh * 8192 + 4096);
  }
  ulonglong2 m0 = mp0[0], m1 = mp1[0];
  ulonglong2 m0n = m0, m1n = m1;

  for (int kt = 0; kt < 16; kt++) {
    int cur = kt & 1;
    asm volatile("s_waitcnt vmcnt(0)" ::: "memory");
    __builtin_amdgcn_s_barrier();
    if (kt < 15) {
      size_t g0 = (size_t)(kt + 1) * 128;
#pragma unroll
      for (int hh = 0; hh < 2; hh++) {
        const unsigned short* kg = kgbase + (g0 + hh * 64) * 512;
        const unsigned short* vg = vgbase + g0 + hh * 64;
        char* kd = kdst[cur ^ 1] + hh * 8192;
        char* vd = vdst[cur ^ 1] + hh * 8192;
        gll16(kg, kd);
        gll16(kg + 32 * 512, kd + 4096);
        gll16(vg, vd);
        gll16(vg + 32 * GS, vd + 4096);
      }
      m0n = mp0[kt + 1];
      m1n = mp1[kt + 1];
    }

    // QK^T for both halves back-to-back
    f32x4 s0[4][2], s1[4][2];
#pragma unroll
    for (int gt = 0; gt < 4; gt++) {
      s0[gt][0] = {0.f, 0.f, 0.f, 0.f}; s0[gt][1] = {0.f, 0.f, 0.f, 0.f};
      s1[gt][0] = {0.f, 0.f, 0.f, 0.f}; s1[gt][1] = {0.f, 0.f, 0.f, 0.f};
    }
    const unsigned short* Kc0 = &Ksh[cur][0];
    const unsigned short* Kc1 = &Ksh[cur][4096];
    __builtin_amdgcn_s_setprio(1);
#pragma unroll
    for (int kc = 0; kc < 2; kc++) {
      bf16x8 ka[4];
#pragma unroll
      for (int gt = 0; gt < 4; gt++)
        ka[gt] = *(const bf16x8*)(Kc0 + ((gt * 2 + kc) * 64 + l) * 8);
#pragma unroll
      for (int gt = 0; gt < 4; gt++) {
        s0[gt][0] = __builtin_amdgcn_mfma_f32_16x16x32_bf16(ka[gt], qb[0][kc], s0[gt][0], 0, 0, 0);
        s0[gt][1] = __builtin_amdgcn_mfma_f32_16x16x32_bf16(ka[gt], qb[1][kc], s0[gt][1], 0, 0, 0);
      }
    }
#pragma unroll
    for (int kc = 0; kc < 2; kc++) {
      bf16x8 ka[4];
#pragma unroll
      for (int gt = 0; gt < 4; gt++)
        ka[gt] = *(const bf16x8*)(Kc1 + ((gt * 2 + kc) * 64 + l) * 8);
#pragma unroll
      for (int gt = 0; gt < 4; gt++) {
        s1[gt][0] = __builtin_amdgcn_mfma_f32_16x16x32_bf16(ka[gt], qb[0][kc], s1[gt][0], 0, 0, 0);
        s1[gt][1] = __builtin_amdgcn_mfma_f32_16x16x32_bf16(ka[gt], qb[1][kc], s1[gt][1], 0, 0, 0);
      }
    }
    __builtin_amdgcn_s_setprio(0);

    // softmax h0 + pack h0
#pragma unroll
    for (int qt = 0; qt < 2; qt++) {
      unsigned long long wmq = qt ? m1.x : m0.x;
      float ls = 0.f;
#pragma unroll
      for (int gt = 0; gt < 4; gt++) {
        unsigned nib = (unsigned)(wmq >> (gt * 16));
        f32x4 pv;
#pragma unroll
        for (int r = 0; r < 4; r++) {
          float e = EXP2(s0[gt][qt][r]);
          pv[r] = ((nib >> (4 * lg + r)) & 1u) ? 0.f : e;
          ls += pv[r];
        }
        s0[gt][qt] = pv;
      }
      lrow[qt] += ls;
#pragma unroll
      for (int gt = 0; gt < 4; gt++) {
        uint2 wp;
        asm("v_cvt_pk_bf16_f32 %0, %1, %2" : "=v"(wp.x) : "v"(s0[gt][qt][0]), "v"(s0[gt][qt][1]));
        asm("v_cvt_pk_bf16_f32 %0, %1, %2" : "=v"(wp.y) : "v"(s0[gt][qt][2]), "v"(s0[gt][qt][3]));
        int chunk = (qt * 2 + (gt >> 1)) * 64 + ((gt & 1) * 2 + (lg >> 1)) * 16 + c;
        *(uint2*)((char*)&Plds[w][0] + chunk * 16 + 8 * (lg & 1)) = wp;
      }
    }

    // softmax h1 (VALU; overlaps h0 pack-write drain)
#pragma unroll
    for (int qt = 0; qt < 2; qt++) {
      unsigned long long wmq = qt ? m1.y : m0.y;
      float ls = 0.f;
#pragma unroll
      for (int gt = 0; gt < 4; gt++) {
        unsigned nib = (unsigned)(wmq >> (gt * 16));
        f32x4 pv;
#pragma unroll
        for (int r = 0; r < 4; r++) {
          float e = EXP2(s1[gt][qt][r]);
          pv[r] = ((nib >> (4 * lg + r)) & 1u) ? 0.f : e;
          ls += pv[r];
        }
        s1[gt][qt] = pv;
      }
      lrow[qt] += ls;
    }

    asm volatile("s_waitcnt lgkmcnt(0)" ::: "memory");
    __builtin_amdgcn_sched_barrier(0);

    // PV h0
    {
      const unsigned short* Vc = &Vsh[cur][0];
      __builtin_amdgcn_s_setprio(1);
#pragma unroll
      for (int kc2 = 0; kc2 < 2; kc2++) {
        bf16x8 pb[2];
#pragma unroll
        for (int qt = 0; qt < 2; qt++)
          pb[qt] = *(const bf16x8*)((const char*)&Plds[w][0] + ((qt * 2 + kc2) * 64 + l) * 16);
        bf16x8 va[4];
#pragma unroll
        for (int vt = 0; vt < 4; vt++)
          va[vt] = *(const bf16x8*)(Vc + ((vt * 2 + kc2) * 64 + l) * 8);
#pragma unroll
        for (int vt = 0; vt < 4; vt++) {
          o[vt][0] = __builtin_amdgcn_mfma_f32_16x16x32_bf16(va[vt], pb[0], o[vt][0], 0, 0, 0);
          o[vt][1] = __builtin_amdgcn_mfma_f32_16x16x32_bf16(va[vt], pb[1], o[vt][1], 0, 0, 0);
        }
      }
      __builtin_amdgcn_s_setprio(0);
    }
    __builtin_amdgcn_sched_barrier(0);   // pin PV(h0) P-reads before pack(h1) P-writes

    // pack h1 (overlaps PV h0 execution)
#pragma unroll
    for (int qt = 0; qt < 2; qt++)
#pragma unroll
      for (int gt = 0; gt < 4; gt++) {
        uint2 wp;
        asm("v_cvt_pk_bf16_f32 %0, %1, %2" : "=v"(wp.x) : "v"(s1[gt][qt][0]), "v"(s1[gt][qt][1]));
        asm("v_cvt_pk_bf16_f32 %0, %1, %2" : "=v"(wp.y) : "v"(s1[gt][qt][2]), "v"(s1[gt][qt][3]));
        int chunk = (qt * 2 + (gt >> 1)) * 64 + ((gt & 1) * 2 + (lg >> 1)) * 16 + c;
        *(uint2*)((char*)&Plds[w][0] + chunk * 16 + 8 * (lg & 1)) = wp;
      }
    asm volatile("s_waitcnt lgkmcnt(0)" ::: "memory");
    __builtin_amdgcn_sched_barrier(0);

    // PV h1
    {
      const unsigned short* Vc = &Vsh[cur][4096];
      __builtin_amdgcn_s_setprio(1);
#pragma unroll
      for (int kc2 = 0; kc2 < 2; kc2++) {
        bf16x8 pb[2];
#pragma unroll
        for (int qt = 0; qt < 2; qt++)
          pb[qt] = *(const bf16x8*)((const char*)&Plds[w][0] + ((qt * 2 + kc2) * 64 + l) * 16);
        bf16x8 va[4];
#pragma unroll
        for (int vt = 0; vt < 4; vt++)
          va[vt] = *(const bf16x8*)(Vc + ((vt * 2 + kc2) * 64 + l) * 8);
#pragma unroll
        for (int vt = 0; vt < 4; vt++) {
          o[vt][0] = __builtin_amdgcn_mfma_f32_16x16x32_bf16(va[vt], pb[0], o[vt][0], 0, 0, 0);
          o[vt][1] = __builtin_amdgcn_mfma_f32_16x16x32_bf16(va[vt], pb[1], o[vt][1], 0, 0, 0);
        }
      }
      __builtin_amdgcn_s_setprio(0);
    }
    m0 = m0n;
    m1 = m1n;
  }

  // epilogue: reduce l across the 4 lanes sharing q, normalize, store
#pragma unroll
  for (int qt = 0; qt < 2; qt++) {
    float lr = lrow[qt];
    lr += __shfl_xor(lr, 16);
    lr += __shfl_xor(lr, 32);
    float inv = lr > 0.f ? 1.0f / lr : 0.f;
    int q = qw + qt * 16 + c;
#pragma unroll
    for (int vt = 0; vt < 4; vt++) {
      ushort4 u;
      u.x = f2bf(o[vt][qt][0] * inv);
      u.y = f2bf(o[vt][qt][1] * inv);
      u.z = f2bf(o[vt][qt][2] * inv);
      u.w = f2bf(o[vt][qt][3] * inv);
      *(ushort4*)(Hd + (size_t)(b * NQS + q) * 512 + hd * 64 + vt * 16 + 4 * lg) = u;
    }
  }
}

// ---------------- launch ----------------

extern "C" void kernel_launch(void* const* d_in, const int* in_sizes, int n_in,
                              void* d_out, int out_size, void* d_ws, size_t ws_size,
                              hipStream_t stream) {
  const float* q = (const float*)d_in[0];
  const float* h = (const float*)d_in[1];
  const void* mask = d_in[2];
  const float* wq = (const float*)d_in[3];
  const float* wk = (const float*)d_in[4];
  const float* wv = (const float*)d_in[5];
  const float* wo = (const float*)d_in[6];
  float* out = (float*)d_out;

  unsigned short* qb_ = (unsigned short*)d_ws;       // 8192*512 each
  unsigned short* hb_ = qb_ + 8192 * 512;
  unsigned short* Qp = hb_ + 8192 * 512;
  unsigned short* Kp = Qp + 8192 * 512;
  unsigned short* Vtp = Kp + 8192 * 512;             // transposed V: [(b*8+h)*64+v][2048]
  unsigned short* Hd = Vtp + 8192 * 512;
  unsigned short* wqt = Hd + 8192 * 512;
  unsigned short* wkvt = wqt + 512 * 512;            // [1024][512]
  unsigned short* wot = wkvt + 1024 * 512;
  unsigned short* maskB16 = wot + 512 * 512;         // 4*2048*128 u16 = 2 MB

  k_prep<<<3584, 256, 0, stream>>>((const float4*)q, (const float4*)h, mask, wq, wk, wv, wo,
                                   (ushort4*)qb_, (ushort4*)hb_, wqt, wkvt, wot, maskB16);
  dim3 gqkv(128, 12);
  k_gemmQKV<<<gqkv, 256, 0, stream>>>(qb_, hb_, wqt, wkvt, Qp, Kp, Vtp);
  k_attn6<<<512, 256, 0, stream>>>(Qp, Kp, Vtp, maskB16, Hd);
  dim3 go(128, 4);
  k_gemm3<1><<<go, 256, 0, stream>>>(Hd, wot, out, nullptr);
}